// Round 5
// baseline (68797.437 us; speedup 1.0000x reference)
//
#include <hip/hip_runtime.h>
#include <hip/hip_bf16.h>

#define B_SZ 1024
#define T_ENC 384
#define T_DEC 128
#define I_SZ 128
#define H_SZ 512

typedef __attribute__((ext_vector_type(8))) short short8;
typedef __attribute__((ext_vector_type(4))) float floatx4;
typedef unsigned short ushort_t;

__device__ __forceinline__ ushort_t f2bf(float x) {
    union { float f; unsigned int i; } v; v.f = x;
    unsigned int u = v.i;
    return (ushort_t)((u + 0x7fffu + ((u >> 16) & 1u)) >> 16);
}
__device__ __forceinline__ float sigm(float x) { return 1.0f / (1.0f + __expf(-x)); }

__device__ __forceinline__ short8 cvt8(float4 a, float4 b) {
    short8 r;
    r[0] = (short)f2bf(a.x); r[1] = (short)f2bf(a.y); r[2] = (short)f2bf(a.z); r[3] = (short)f2bf(a.w);
    r[4] = (short)f2bf(b.x); r[5] = (short)f2bf(b.y); r[6] = (short)f2bf(b.z); r[7] = (short)f2bf(b.w);
    return r;
}

struct Params {
    const float* x;
    const float* Wih0; const float* Whh0; const float* bih0; const float* bhh0;
    const float* Wih1; const float* Whh1; const float* bih1; const float* bhh1;
    const float* fcw;  const float* fcb;
    float* out;
    ushort_t* h0a; ushort_t* h0b; ushort_t* h1a; ushort_t* h1b;
    ushort_t* dec_in;
    unsigned* ctr;
};

#define NCH0 5   // L0: K=640, K/4=160 = 5 chunks of 32
#define NCH1 8   // L1: K=1024, K/4=256 = 8 chunks
#define NCHF 4   // fc: K=512, K/4=128 = 4 chunks

// 64-block group barrier: monotonically-increasing counter, release/acquire at agent scope.
// Deadlock-free because grid(512) == co-resident capacity (2 blocks/CU by construction:
// launch_bounds caps VGPR at 256, LDS 32KB/block).
__device__ __forceinline__ void group_barrier(unsigned* c, unsigned target) {
    __syncthreads();
    if (threadIdx.x == 0) {
        __threadfence();
        __hip_atomic_fetch_add(c, 1u, __ATOMIC_RELEASE, __HIP_MEMORY_SCOPE_AGENT);
        while (__hip_atomic_load(c, __ATOMIC_ACQUIRE, __HIP_MEMORY_SCOPE_AGENT) < target)
            __builtin_amdgcn_s_sleep(2);
        __threadfence();
    }
    __syncthreads();
}

// One LSTM cell step for this block's (128 rows x 16 h-cols), W in registers.
// wave = K-quarter kq; per mt (16 rows): 4-gate partials -> LDS -> per-thread epilogue.
// c lives in creg[8] (thread owns cell (mt, tid>>4, tid&15) forever).
template<int NCH, int MODE>   // MODE 1: A1 fp32 (x), else bf16
__device__ __forceinline__ void run_cell(
    const void* __restrict__ A1, int lda1, int K1,
    const ushort_t* __restrict__ A2,
    const short8* wf, const float* bias4, float* creg,
    ushort_t* __restrict__ hout,
    int row0, int hcol0, int kq,
    float (*zbuf)[4][4][256])
{
    const int tid  = threadIdx.x;
    const int lane = tid & 63;
    const int quad = lane >> 4;
    const int l15  = lane & 15;
#pragma unroll
    for (int mt = 0; mt < 8; ++mt) {
        floatx4 acc[4];
#pragma unroll
        for (int g = 0; g < 4; ++g) acc[g] = (floatx4){0.f, 0.f, 0.f, 0.f};
        const int arow = row0 + mt * 16 + l15;
#pragma unroll
        for (int kc = 0; kc < NCH; ++kc) {
            const int k = kq * (NCH * 32) + kc * 32;
            short8 a;
            if (k < K1) {
                if (MODE == 1) {
                    const float* s = (const float*)A1 + (size_t)arow * lda1 + k + quad * 8;
                    a = cvt8(*(const float4*)s, *(const float4*)(s + 4));
                } else {
                    a = *(const short8*)((const ushort_t*)A1 + (size_t)arow * lda1 + k + quad * 8);
                }
            } else {
                a = *(const short8*)(A2 + (size_t)arow * H_SZ + (k - K1) + quad * 8);
            }
#pragma unroll
            for (int g = 0; g < 4; ++g)
                acc[g] = __builtin_amdgcn_mfma_f32_16x16x32_bf16(a, wf[g * NCH + kc], acc[g], 0, 0, 0);
        }
#pragma unroll
        for (int g = 0; g < 4; ++g)
#pragma unroll
            for (int i = 0; i < 4; ++i)
                zbuf[mt & 1][kq][g][(quad * 4 + i) * 16 + l15] = acc[g][i];
        __syncthreads();
        {
            const int r = tid >> 4, cc = tid & 15;
            float zi = bias4[0], zf = bias4[1], zg = bias4[2], zo = bias4[3];
#pragma unroll
            for (int kk = 0; kk < 4; ++kk) {
                zi += zbuf[mt & 1][kk][0][r * 16 + cc];
                zf += zbuf[mt & 1][kk][1][r * 16 + cc];
                zg += zbuf[mt & 1][kk][2][r * 16 + cc];
                zo += zbuf[mt & 1][kk][3][r * 16 + cc];
            }
            const int grow = row0 + mt * 16 + r;
            const float cn = sigm(zf) * creg[mt] + sigm(zi) * tanhf(zg);
            creg[mt] = cn;
            hout[(size_t)grow * H_SZ + hcol0 + cc] = f2bf(sigm(zo) * tanhf(cn));
        }
        // half (mt&1) is next rewritten at mt+2, which is ordered after the
        // __syncthreads of mt+1 -> no extra sync needed
    }
}

// fc head: 16 out-cols per fc-block; writes out[:, t, :] (fp32) and dec_in (bf16)
template<int NCH>
__device__ __forceinline__ void run_fc(
    const ushort_t* __restrict__ h1,
    const short8* wf, float bias, float* __restrict__ outp, ushort_t* __restrict__ dec_in,
    int row0, int ocol0, int kq,
    float (*zbuf)[4][4][256])
{
    const int tid  = threadIdx.x;
    const int lane = tid & 63;
    const int quad = lane >> 4;
    const int l15  = lane & 15;
#pragma unroll
    for (int mt = 0; mt < 8; ++mt) {
        floatx4 acc = (floatx4){0.f, 0.f, 0.f, 0.f};
        const int arow = row0 + mt * 16 + l15;
#pragma unroll
        for (int kc = 0; kc < NCH; ++kc) {
            const int k = kq * (NCH * 32) + kc * 32;
            short8 a = *(const short8*)(h1 + (size_t)arow * H_SZ + k + quad * 8);
            acc = __builtin_amdgcn_mfma_f32_16x16x32_bf16(a, wf[kc], acc, 0, 0, 0);
        }
#pragma unroll
        for (int i = 0; i < 4; ++i)
            zbuf[mt & 1][kq][0][(quad * 4 + i) * 16 + l15] = acc[i];
        __syncthreads();
        {
            const int r = tid >> 4, cc = tid & 15;
            float v = bias;
#pragma unroll
            for (int kk = 0; kk < 4; ++kk) v += zbuf[mt & 1][kk][0][r * 16 + cc];
            const int grow = row0 + mt * 16 + r;
            outp[(size_t)grow * (T_DEC * I_SZ) + ocol0 + cc] = v;
            dec_in[(size_t)grow * I_SZ + ocol0 + cc] = f2bf(v);
        }
    }
}

// 512 blocks: grp = bid&7 (batch rows grp*128.., XCD-affine), q = bid>>3:
// q<32 -> L0 block (h-col group q), q>=32 -> L1 block (h-col group q-32), q<8 also fc.
__global__ __launch_bounds__(256, 2) void persist(Params p)
{
    const int tid  = threadIdx.x;
    const int wave = tid >> 6;
    const int lane = tid & 63;
    const int quad = lane >> 4;
    const int l15  = lane & 15;
    const int bid  = blockIdx.x;
    const int grp  = bid & 7;
    const int q    = bid >> 3;
    const bool isL0 = (q < 32);
    const bool isFC = (q < 8);
    const int hcg  = isL0 ? q : (q - 32);
    const int row0 = grp * 128;
    const int hcol0 = hcg * 16;

    __shared__ float zbuf[2][4][4][256];   // 32 KB

    ushort_t* h0buf[2] = { p.h0a, p.h0b };
    ushort_t* h1buf[2] = { p.h1a, p.h1b };
    unsigned* bar = p.ctr + grp * 32;

    // ---- load persistent W fragments (fp32 -> bf16, once) ----
    short8 wf[4 * NCH1];
    short8 wfc[NCHF];
    if (isL0) {
#pragma unroll
        for (int g = 0; g < 4; ++g)
#pragma unroll
            for (int kc = 0; kc < NCH0; ++kc) {
                const int k = wave * (NCH0 * 32) + kc * 32 + quad * 8;
                const int zrow = g * H_SZ + hcol0 + l15;
                const float* s = (k < I_SZ) ? (p.Wih0 + (size_t)zrow * I_SZ + k)
                                            : (p.Whh0 + (size_t)zrow * H_SZ + (k - I_SZ));
                wf[g * NCH0 + kc] = cvt8(*(const float4*)s, *(const float4*)(s + 4));
            }
        if (isFC) {
#pragma unroll
            for (int kc = 0; kc < NCHF; ++kc) {
                const int k = wave * (NCHF * 32) + kc * 32 + quad * 8;
                const int zrow = q * 16 + l15;   // out-col
                const float* s = p.fcw + (size_t)zrow * H_SZ + k;
                wfc[kc] = cvt8(*(const float4*)s, *(const float4*)(s + 4));
            }
        }
    } else {
#pragma unroll
        for (int g = 0; g < 4; ++g)
#pragma unroll
            for (int kc = 0; kc < NCH1; ++kc) {
                const int k = wave * (NCH1 * 32) + kc * 32 + quad * 8;
                const int zrow = g * H_SZ + hcol0 + l15;
                const float* s = (k < H_SZ) ? (p.Wih1 + (size_t)zrow * H_SZ + k)
                                            : (p.Whh1 + (size_t)zrow * H_SZ + (k - H_SZ));
                wf[g * NCH1 + kc] = cvt8(*(const float4*)s, *(const float4*)(s + 4));
            }
    }

    float bias4[4];
    {
        const int col = hcol0 + (tid & 15);
        const float* bi = isL0 ? p.bih0 : p.bih1;
        const float* bh = isL0 ? p.bhh0 : p.bhh1;
#pragma unroll
        for (int g = 0; g < 4; ++g) bias4[g] = bi[g * H_SZ + col] + bh[g * H_SZ + col];
    }
    const float fcbias = isFC ? p.fcb[q * 16 + (tid & 15)] : 0.f;

    float creg[8];
#pragma unroll
    for (int i = 0; i < 8; ++i) creg[i] = 0.f;

    unsigned epoch = 0;

    // ---------- encoder, pipelined: superstep s runs L0(s) and L1(s-1) ----------
    for (int s = 0; s <= T_ENC; ++s) {
        if (isL0) {
            if (s < T_ENC)
                run_cell<NCH0, 1>(p.x + (size_t)s * I_SZ, T_ENC * I_SZ, I_SZ,
                                  h0buf[(s + 1) & 1], wf, bias4, creg,
                                  h0buf[s & 1], row0, hcol0, wave, zbuf);
        } else {
            if (s >= 1)
                run_cell<NCH1, 0>(h0buf[(s - 1) & 1], H_SZ, H_SZ,
                                  h1buf[s & 1], wf, bias4, creg,
                                  h1buf[(s + 1) & 1], row0, hcol0, wave, zbuf);
        }
        ++epoch; group_barrier(bar, 64u * epoch);
    }

    // ---------- decoder: 3 phases per token ----------
    for (int t = 0; t < T_DEC; ++t) {
        if (isL0) {
            if (t == 0)
                run_cell<NCH0, 1>(p.x + (size_t)(T_ENC - 1) * I_SZ, T_ENC * I_SZ, I_SZ,
                                  h0buf[1], wf, bias4, creg, h0buf[0], row0, hcol0, wave, zbuf);
            else
                run_cell<NCH0, 0>(p.dec_in, I_SZ, I_SZ,
                                  h0buf[(t + 1) & 1], wf, bias4, creg,
                                  h0buf[t & 1], row0, hcol0, wave, zbuf);
        }
        ++epoch; group_barrier(bar, 64u * epoch);

        if (!isL0)
            run_cell<NCH1, 0>(h0buf[t & 1], H_SZ, H_SZ,
                              h1buf[(t + 1) & 1], wf, bias4, creg,
                              h1buf[t & 1], row0, hcol0, wave, zbuf);
        ++epoch; group_barrier(bar, 64u * epoch);

        if (isFC)
            run_fc<NCHF>(h1buf[t & 1], wfc, fcbias, p.out + (size_t)t * I_SZ, p.dec_in,
                         row0, q * 16, wave, zbuf);
        ++epoch; group_barrier(bar, 64u * epoch);
    }
}

extern "C" void kernel_launch(void* const* d_in, const int* in_sizes, int n_in,
                              void* d_out, int out_size, void* d_ws, size_t ws_size,
                              hipStream_t stream)
{
    Params prm;
    prm.x    = (const float*)d_in[0];
    prm.Wih0 = (const float*)d_in[1];
    prm.Whh0 = (const float*)d_in[2];
    prm.bih0 = (const float*)d_in[3];
    prm.bhh0 = (const float*)d_in[4];
    prm.Wih1 = (const float*)d_in[5];
    prm.Whh1 = (const float*)d_in[6];
    prm.bih1 = (const float*)d_in[7];
    prm.bhh1 = (const float*)d_in[8];
    prm.fcw  = (const float*)d_in[9];
    prm.fcb  = (const float*)d_in[10];
    prm.out  = (float*)d_out;

    const size_t HB2 = (size_t)B_SZ * H_SZ * 2;   // 1 MB bf16
    char* w = (char*)d_ws;
    prm.h0a = (ushort_t*)w;    w += HB2;
    prm.h0b = (ushort_t*)w;    w += HB2;
    prm.h1a = (ushort_t*)w;    w += HB2;
    prm.h1b = (ushort_t*)w;    w += HB2;
    prm.dec_in = (ushort_t*)w; w += (size_t)B_SZ * I_SZ * 2;
    prm.ctr = (unsigned*)w;    w += 8 * 32 * sizeof(unsigned);

    hipMemsetAsync(prm.h0a, 0, HB2, stream);
    hipMemsetAsync(prm.h0b, 0, HB2, stream);
    hipMemsetAsync(prm.h1a, 0, HB2, stream);
    hipMemsetAsync(prm.h1b, 0, HB2, stream);
    hipMemsetAsync(prm.ctr, 0, 8 * 32 * sizeof(unsigned), stream);

    // Plain launch (no cooperative API): barriers are per-64-block group only,
    // and grid(512) == guaranteed co-resident capacity (2 blocks/CU).
    persist<<<dim3(512), dim3(256), 0, stream>>>(prm);
}

// Round 6
// 23231.772 us; speedup vs baseline: 2.9614x; 2.9614x over previous
//
#include <hip/hip_runtime.h>
#include <hip/hip_bf16.h>

#define B_SZ 1024
#define T_ENC 384
#define T_DEC 128
#define I_SZ 128
#define H_SZ 512

typedef __attribute__((ext_vector_type(8))) short short8;
typedef __attribute__((ext_vector_type(4))) float floatx4;
typedef unsigned short ushort_t;

__device__ __forceinline__ ushort_t f2bf(float x) {
    union { float f; unsigned int i; } v; v.f = x;
    unsigned int u = v.i;
    return (ushort_t)((u + 0x7fffu + ((u >> 16) & 1u)) >> 16);
}
__device__ __forceinline__ float sigm(float x) { return 1.0f / (1.0f + __expf(-x)); }

__device__ __forceinline__ short8 cvt8(float4 a, float4 b) {
    short8 r;
    r[0] = (short)f2bf(a.x); r[1] = (short)f2bf(a.y); r[2] = (short)f2bf(a.z); r[3] = (short)f2bf(a.w);
    r[4] = (short)f2bf(b.x); r[5] = (short)f2bf(b.y); r[6] = (short)f2bf(b.z); r[7] = (short)f2bf(b.w);
    return r;
}

struct Params {
    const float* x;
    const float* Wih0; const float* Whh0; const float* bih0; const float* bhh0;
    const float* Wih1; const float* Whh1; const float* bih1; const float* bhh1;
    const float* fcw;  const float* fcb;
    float* out;
    ushort_t* h0a; ushort_t* h0b; ushort_t* h1a; ushort_t* h1b;
    ushort_t* dec_in;
    unsigned* ctr;
};

#define NCH0 5   // L0: K=640, K/4=160 = 5 chunks of 32
#define NCH1 8   // L1: K=1024, K/4=256 = 8 chunks
#define NCHF 4   // fc: K=512, K/4=128 = 4 chunks

// 64-block group barrier.
// R5 lesson: ACQUIRE on every poll load emits a cache invalidate per spin
// iteration (per-XCD L2 non-coherence makes agent-acquire = L2 inv) -> the
// poll storm invalidated L2 continuously and stalled the whole chip (89us per
// barrier, MfmaUtil 2%). Fix: exactly ONE release fence (on the add), RELAXED
// agent-scope polling (sc-bit read past L2, no invalidate), ONE acquire fence
// after exit.
__device__ __forceinline__ void group_barrier(unsigned* c, unsigned target) {
    __syncthreads();   // compiler emits vmcnt(0) drain -> all waves' stores visible in L2
    if (threadIdx.x == 0) {
        __hip_atomic_fetch_add(c, 1u, __ATOMIC_RELEASE, __HIP_MEMORY_SCOPE_AGENT);
        while (__hip_atomic_load(c, __ATOMIC_RELAXED, __HIP_MEMORY_SCOPE_AGENT) < target)
            __builtin_amdgcn_s_sleep(8);
        __builtin_amdgcn_fence(__ATOMIC_ACQUIRE, "agent");
    }
    __syncthreads();
}

// One LSTM cell step for this block's (128 rows x 16 h-cols), W in registers.
// wave = K-quarter kq; per mt (16 rows): 4-gate partials -> LDS -> per-thread epilogue.
// c lives in creg[8] (thread owns cell (mt, tid>>4, tid&15) forever).
template<int NCH, int MODE>   // MODE 1: A1 fp32 (x), else bf16
__device__ __forceinline__ void run_cell(
    const void* __restrict__ A1, int lda1, int K1,
    const ushort_t* __restrict__ A2,
    const short8* wf, const float* bias4, float* creg,
    ushort_t* __restrict__ hout,
    int row0, int hcol0, int kq,
    float (*zbuf)[4][4][256])
{
    const int tid  = threadIdx.x;
    const int lane = tid & 63;
    const int quad = lane >> 4;
    const int l15  = lane & 15;
#pragma unroll
    for (int mt = 0; mt < 8; ++mt) {
        floatx4 acc[4];
#pragma unroll
        for (int g = 0; g < 4; ++g) acc[g] = (floatx4){0.f, 0.f, 0.f, 0.f};
        const int arow = row0 + mt * 16 + l15;
#pragma unroll
        for (int kc = 0; kc < NCH; ++kc) {
            const int k = kq * (NCH * 32) + kc * 32;
            short8 a;
            if (k < K1) {
                if (MODE == 1) {
                    const float* s = (const float*)A1 + (size_t)arow * lda1 + k + quad * 8;
                    a = cvt8(*(const float4*)s, *(const float4*)(s + 4));
                } else {
                    a = *(const short8*)((const ushort_t*)A1 + (size_t)arow * lda1 + k + quad * 8);
                }
            } else {
                a = *(const short8*)(A2 + (size_t)arow * H_SZ + (k - K1) + quad * 8);
            }
#pragma unroll
            for (int g = 0; g < 4; ++g)
                acc[g] = __builtin_amdgcn_mfma_f32_16x16x32_bf16(a, wf[g * NCH + kc], acc[g], 0, 0, 0);
        }
#pragma unroll
        for (int g = 0; g < 4; ++g)
#pragma unroll
            for (int i = 0; i < 4; ++i)
                zbuf[mt & 1][kq][g][(quad * 4 + i) * 16 + l15] = acc[g][i];
        __syncthreads();
        {
            const int r = tid >> 4, cc = tid & 15;
            float zi = bias4[0], zf = bias4[1], zg = bias4[2], zo = bias4[3];
#pragma unroll
            for (int kk = 0; kk < 4; ++kk) {
                zi += zbuf[mt & 1][kk][0][r * 16 + cc];
                zf += zbuf[mt & 1][kk][1][r * 16 + cc];
                zg += zbuf[mt & 1][kk][2][r * 16 + cc];
                zo += zbuf[mt & 1][kk][3][r * 16 + cc];
            }
            const int grow = row0 + mt * 16 + r;
            const float cn = sigm(zf) * creg[mt] + sigm(zi) * tanhf(zg);
            creg[mt] = cn;
            hout[(size_t)grow * H_SZ + hcol0 + cc] = f2bf(sigm(zo) * tanhf(cn));
        }
        // half (mt&1) is next rewritten at mt+2, ordered after the
        // __syncthreads of mt+1 -> no extra sync needed
    }
}

// fc head: 16 out-cols per fc-block; writes out[:, t, :] (fp32) and dec_in (bf16)
template<int NCH>
__device__ __forceinline__ void run_fc(
    const ushort_t* __restrict__ h1,
    const short8* wf, float bias, float* __restrict__ outp, ushort_t* __restrict__ dec_in,
    int row0, int ocol0, int kq,
    float (*zbuf)[4][4][256])
{
    const int tid  = threadIdx.x;
    const int lane = tid & 63;
    const int quad = lane >> 4;
    const int l15  = lane & 15;
#pragma unroll
    for (int mt = 0; mt < 8; ++mt) {
        floatx4 acc = (floatx4){0.f, 0.f, 0.f, 0.f};
        const int arow = row0 + mt * 16 + l15;
#pragma unroll
        for (int kc = 0; kc < NCH; ++kc) {
            const int k = kq * (NCH * 32) + kc * 32;
            short8 a = *(const short8*)(h1 + (size_t)arow * H_SZ + k + quad * 8);
            acc = __builtin_amdgcn_mfma_f32_16x16x32_bf16(a, wf[kc], acc, 0, 0, 0);
        }
#pragma unroll
        for (int i = 0; i < 4; ++i)
            zbuf[mt & 1][kq][0][(quad * 4 + i) * 16 + l15] = acc[i];
        __syncthreads();
        {
            const int r = tid >> 4, cc = tid & 15;
            float v = bias;
#pragma unroll
            for (int kk = 0; kk < 4; ++kk) v += zbuf[mt & 1][kk][0][r * 16 + cc];
            const int grow = row0 + mt * 16 + r;
            outp[(size_t)grow * (T_DEC * I_SZ) + ocol0 + cc] = v;
            dec_in[(size_t)grow * I_SZ + ocol0 + cc] = f2bf(v);
        }
    }
}

// 512 blocks: grp = bid&7 (batch rows grp*128.., XCD-affine for locality), q = bid>>3:
// q<32 -> L0 block (h-col group q), q>=32 -> L1 block (h-col group q-32), q<8 also fc.
__global__ __launch_bounds__(256, 2) void persist(Params p)
{
    const int tid  = threadIdx.x;
    const int wave = tid >> 6;
    const int lane = tid & 63;
    const int quad = lane >> 4;
    const int l15  = lane & 15;
    const int bid  = blockIdx.x;
    const int grp  = bid & 7;
    const int q    = bid >> 3;
    const bool isL0 = (q < 32);
    const bool isFC = (q < 8);
    const int hcg  = isL0 ? q : (q - 32);
    const int row0 = grp * 128;
    const int hcol0 = hcg * 16;

    __shared__ float zbuf[2][4][4][256];   // 32 KB

    ushort_t* h0buf[2] = { p.h0a, p.h0b };
    ushort_t* h1buf[2] = { p.h1a, p.h1b };
    unsigned* bar = p.ctr + grp * 32;

    // ---- load persistent W fragments (fp32 -> bf16, once) ----
    short8 wf[4 * NCH1];
    short8 wfc[NCHF];
    if (isL0) {
#pragma unroll
        for (int g = 0; g < 4; ++g)
#pragma unroll
            for (int kc = 0; kc < NCH0; ++kc) {
                const int k = wave * (NCH0 * 32) + kc * 32 + quad * 8;
                const int zrow = g * H_SZ + hcol0 + l15;
                const float* s = (k < I_SZ) ? (p.Wih0 + (size_t)zrow * I_SZ + k)
                                            : (p.Whh0 + (size_t)zrow * H_SZ + (k - I_SZ));
                wf[g * NCH0 + kc] = cvt8(*(const float4*)s, *(const float4*)(s + 4));
            }
        if (isFC) {
#pragma unroll
            for (int kc = 0; kc < NCHF; ++kc) {
                const int k = wave * (NCHF * 32) + kc * 32 + quad * 8;
                const int zrow = q * 16 + l15;   // out-col
                const float* s = p.fcw + (size_t)zrow * H_SZ + k;
                wfc[kc] = cvt8(*(const float4*)s, *(const float4*)(s + 4));
            }
        }
    } else {
#pragma unroll
        for (int g = 0; g < 4; ++g)
#pragma unroll
            for (int kc = 0; kc < NCH1; ++kc) {
                const int k = wave * (NCH1 * 32) + kc * 32 + quad * 8;
                const int zrow = g * H_SZ + hcol0 + l15;
                const float* s = (k < H_SZ) ? (p.Wih1 + (size_t)zrow * H_SZ + k)
                                            : (p.Whh1 + (size_t)zrow * H_SZ + (k - H_SZ));
                wf[g * NCH1 + kc] = cvt8(*(const float4*)s, *(const float4*)(s + 4));
            }
    }

    float bias4[4];
    {
        const int col = hcol0 + (tid & 15);
        const float* bi = isL0 ? p.bih0 : p.bih1;
        const float* bh = isL0 ? p.bhh0 : p.bhh1;
#pragma unroll
        for (int g = 0; g < 4; ++g) bias4[g] = bi[g * H_SZ + col] + bh[g * H_SZ + col];
    }
    const float fcbias = isFC ? p.fcb[q * 16 + (tid & 15)] : 0.f;

    float creg[8];
#pragma unroll
    for (int i = 0; i < 8; ++i) creg[i] = 0.f;

    unsigned epoch = 0;

    // ---------- encoder, pipelined: superstep s runs L0(s) and L1(s-1) ----------
    for (int s = 0; s <= T_ENC; ++s) {
        if (isL0) {
            if (s < T_ENC)
                run_cell<NCH0, 1>(p.x + (size_t)s * I_SZ, T_ENC * I_SZ, I_SZ,
                                  h0buf[(s + 1) & 1], wf, bias4, creg,
                                  h0buf[s & 1], row0, hcol0, wave, zbuf);
        } else {
            if (s >= 1)
                run_cell<NCH1, 0>(h0buf[(s - 1) & 1], H_SZ, H_SZ,
                                  h1buf[s & 1], wf, bias4, creg,
                                  h1buf[(s + 1) & 1], row0, hcol0, wave, zbuf);
        }
        ++epoch; group_barrier(bar, 64u * epoch);
    }

    // ---------- decoder: 3 phases per token ----------
    for (int t = 0; t < T_DEC; ++t) {
        if (isL0) {
            if (t == 0)
                run_cell<NCH0, 1>(p.x + (size_t)(T_ENC - 1) * I_SZ, T_ENC * I_SZ, I_SZ,
                                  h0buf[1], wf, bias4, creg, h0buf[0], row0, hcol0, wave, zbuf);
            else
                run_cell<NCH0, 0>(p.dec_in, I_SZ, I_SZ,
                                  h0buf[(t + 1) & 1], wf, bias4, creg,
                                  h0buf[t & 1], row0, hcol0, wave, zbuf);
        }
        ++epoch; group_barrier(bar, 64u * epoch);

        if (!isL0)
            run_cell<NCH1, 0>(h0buf[t & 1], H_SZ, H_SZ,
                              h1buf[(t + 1) & 1], wf, bias4, creg,
                              h1buf[t & 1], row0, hcol0, wave, zbuf);
        ++epoch; group_barrier(bar, 64u * epoch);

        if (isFC)
            run_fc<NCHF>(h1buf[t & 1], wfc, fcbias, p.out + (size_t)t * I_SZ, p.dec_in,
                         row0, q * 16, wave, zbuf);
        ++epoch; group_barrier(bar, 64u * epoch);
    }
}

extern "C" void kernel_launch(void* const* d_in, const int* in_sizes, int n_in,
                              void* d_out, int out_size, void* d_ws, size_t ws_size,
                              hipStream_t stream)
{
    Params prm;
    prm.x    = (const float*)d_in[0];
    prm.Wih0 = (const float*)d_in[1];
    prm.Whh0 = (const float*)d_in[2];
    prm.bih0 = (const float*)d_in[3];
    prm.bhh0 = (const float*)d_in[4];
    prm.Wih1 = (const float*)d_in[5];
    prm.Whh1 = (const float*)d_in[6];
    prm.bih1 = (const float*)d_in[7];
    prm.bhh1 = (const float*)d_in[8];
    prm.fcw  = (const float*)d_in[9];
    prm.fcb  = (const float*)d_in[10];
    prm.out  = (float*)d_out;

    const size_t HB2 = (size_t)B_SZ * H_SZ * 2;   // 1 MB bf16
    char* w = (char*)d_ws;
    prm.h0a = (ushort_t*)w;    w += HB2;
    prm.h0b = (ushort_t*)w;    w += HB2;
    prm.h1a = (ushort_t*)w;    w += HB2;
    prm.h1b = (ushort_t*)w;    w += HB2;
    prm.dec_in = (ushort_t*)w; w += (size_t)B_SZ * I_SZ * 2;
    prm.ctr = (unsigned*)w;    w += 8 * 32 * sizeof(unsigned);

    hipMemsetAsync(prm.h0a, 0, HB2, stream);
    hipMemsetAsync(prm.h0b, 0, HB2, stream);
    hipMemsetAsync(prm.h1a, 0, HB2, stream);
    hipMemsetAsync(prm.h1b, 0, HB2, stream);
    hipMemsetAsync(prm.ctr, 0, 8 * 32 * sizeof(unsigned), stream);

    // Plain launch (no cooperative API): barriers are per-64-block group only,
    // and grid(512) == guaranteed co-resident capacity (2 blocks/CU).
    persist<<<dim3(512), dim3(256), 0, stream>>>(prm);
}